// Round 14
// baseline (182.592 us; speedup 1.0000x reference)
//
#include <hip/hip_runtime.h>
#include <stdint.h>
#include <math.h>

#define N_NODES   100000
#define N_EDGES   1600000
#define NFEAT     100
#define HIDDEN    32
#define OUTC      2

#define BUCK_BITS 7
#define BUCK_SZ   128
#define NBUCK     782                       // ceil(100000/128)
#define PADB      4096                      // padded window per bucket
#define DUMMY     N_NODES                   // zero-row source for padding

#define PART_NB   512
#define PART_CHUNK ((N_EDGES + PART_NB - 1) / PART_NB)   // 3125
#define PART_SLOTS 4                        // ceil(3125/1024)
#define SORT_SLOTS 16

typedef float fx4 __attribute__((ext_vector_type(4)));

// ---------------------------------------------------------------------------
// JAX threefry2x32, key=(0,42), partitionable: bits(f) = o0^o1
// ---------------------------------------------------------------------------
__device__ __forceinline__ uint32_t rotl32(uint32_t x, int r) {
    return (x << r) | (x >> (32 - r));
}

__device__ __forceinline__ uint32_t threefry_bits(uint32_t f) {
    const uint32_t ks0 = 0u;
    const uint32_t ks1 = 42u;
    const uint32_t ks2 = 0x1BD11BDAu ^ 0u ^ 42u;
    uint32_t x0 = 0u + ks0;
    uint32_t x1 = f  + ks1;
#define TF_ROUND(r) { x0 += x1; x1 = rotl32(x1, (r)); x1 ^= x0; }
    TF_ROUND(13) TF_ROUND(15) TF_ROUND(26) TF_ROUND(6)
    x0 += ks1; x1 += ks2 + 1u;
    TF_ROUND(17) TF_ROUND(29) TF_ROUND(16) TF_ROUND(24)
    x0 += ks2; x1 += ks0 + 2u;
    TF_ROUND(13) TF_ROUND(15) TF_ROUND(26) TF_ROUND(6)
    x0 += ks0; x1 += ks1 + 3u;
    TF_ROUND(17) TF_ROUND(29) TF_ROUND(16) TF_ROUND(24)
    x0 += ks1; x1 += ks2 + 4u;
    TF_ROUND(13) TF_ROUND(15) TF_ROUND(26) TF_ROUND(6)
    x0 += ks2; x1 += ks0 + 5u;
#undef TF_ROUND
    return x0 ^ x1;
}

__device__ __forceinline__ bool dropout_keep(uint32_t f) {
    uint32_t bits = threefry_bits(f);
    float u = __uint_as_float((bits >> 9) | 0x3f800000u) - 1.0f;
    return u < 0.8f;
}

// float -> bf16 (RNE); packed bf16 pair unpack
__device__ __forceinline__ uint16_t f2bf(float f) {
    uint32_t b = __float_as_uint(f);
    uint32_t lsb = (b >> 16) & 1u;
    b += 0x7fffu + lsb;
    return (uint16_t)(b >> 16);
}
__device__ __forceinline__ float bflo(uint32_t u) {
    return __uint_as_float(u << 16);
}
__device__ __forceinline__ float bfhi(uint32_t u) {
    return __uint_as_float(u & 0xffff0000u);
}

// ---------------------------------------------------------------------------
// 0. Seed bucket cursors; zero the DUMMY rows of h0b and h2s
// ---------------------------------------------------------------------------
__global__ __launch_bounds__(256) void k_init(int* __restrict__ bcur,
                                              uint32_t* __restrict__ h0d,
                                              float* __restrict__ h2d) {
    int i = blockIdx.x * 256 + threadIdx.x;
    if (i < NBUCK) bcur[i] = i * PADB;
    if (i < 16) h0d[(size_t)DUMMY * 16 + i] = 0u;       // 32 bf16 = 16 dwords
    if (i >= 16 && i < 18) h2d[(size_t)DUMMY * 2 + (i - 16)] = 0.0f;
}

// ---------------------------------------------------------------------------
// 1. Partition into padded bucket windows (register-stash, one edge read).
//    512 blocks -> 2 blocks/CU (vs 1 at 256): doubled occupancy.
// ---------------------------------------------------------------------------
__global__ __launch_bounds__(1024) void k_part(const int* __restrict__ src,
                                               const int* __restrict__ dst,
                                               int* __restrict__ bcur,
                                               uint32_t* __restrict__ part) {
    __shared__ int h4[4][NBUCK];
    __shared__ int c4[4][NBUCK];
    const int t = threadIdx.x;
    const int w = (t >> 6) & 3;
    const int base = blockIdx.x * PART_CHUNK;
    const int lim = min(base + PART_CHUNK, N_EDGES);
    for (int i = t; i < 4 * NBUCK; i += 1024) ((int*)h4)[i] = 0;
    __syncthreads();
    uint32_t ed[PART_SLOTS];
    int      eb[PART_SLOTS];
#pragma unroll
    for (int k = 0; k < PART_SLOTS; ++k) {
        int e = base + t + k * 1024;
        bool v = e < lim;
        int d = v ? dst[e] : 0;
        int s = v ? src[e] : 0;
        eb[k] = v ? (d >> BUCK_BITS) : -1;
        ed[k] = ((uint32_t)(d & (BUCK_SZ - 1)) << 17) | (uint32_t)s;
        if (v) atomicAdd(&h4[w][d >> BUCK_BITS], 1);
    }
    __syncthreads();
    if (t < NBUCK) {
        int c0 = h4[0][t], c1 = h4[1][t], c2 = h4[2][t], c3 = h4[3][t];
        int tot = c0 + c1 + c2 + c3;
        int g = tot ? atomicAdd(&bcur[t], tot) : 0;
        c4[0][t] = g;
        c4[1][t] = g + c0;
        c4[2][t] = g + c0 + c1;
        c4[3][t] = g + c0 + c1 + c2;
    }
    __syncthreads();
#pragma unroll
    for (int k = 0; k < PART_SLOTS; ++k) {
        if (eb[k] >= 0) {
            int pos = atomicAdd(&c4[w][eb[k]], 1);
            part[pos] = ed[k];
        }
    }
}

// ---------------------------------------------------------------------------
// 2. Per-bucket counting sort -> csr with rows PADDED to x8 (DUMMY fill),
//    rowbeg, deg (real), dinv. Wave-shuffle scan.
// ---------------------------------------------------------------------------
__global__ __launch_bounds__(256) void k_sort(const uint32_t* __restrict__ part,
                                              const int* __restrict__ bcur,
                                              int* __restrict__ csr_src,
                                              int* __restrict__ rowbeg,
                                              int* __restrict__ deg,
                                              float* __restrict__ dinv) {
    __shared__ int cnt4[4][BUCK_SZ];
    __shared__ int cur4[4][BUCK_SZ];
    __shared__ int w0tot;
    const int b = blockIdx.x;
    const int t = threadIdx.x;
    const int w = t >> 6;
    const int nbase = b * BUCK_SZ;
    const int bb = b * PADB;
    const int be = bcur[b];
    for (int i = t; i < 4 * BUCK_SZ; i += 256) ((int*)cnt4)[i] = 0;
    __syncthreads();
    uint32_t ed[SORT_SLOTS];
#pragma unroll
    for (int k = 0; k < SORT_SLOTS; ++k) {
        int j = bb + t + k * 256;
        bool v = j < be;
        uint32_t val = v ? part[j] : 0xFFFFFFFFu;
        ed[k] = val;
        if (v) atomicAdd(&cnt4[w][(val >> 17) & (BUCK_SZ - 1)], 1);
    }
    __syncthreads();
    int c0 = 0, c1 = 0, c2 = 0, tot = 0, ptot = 0;
    if (t < BUCK_SZ) {
        c0 = cnt4[0][t]; c1 = cnt4[1][t]; c2 = cnt4[2][t];
        tot = c0 + c1 + c2 + cnt4[3][t];
        ptot = (tot + 7) & ~7;               // pad to x8
    }
    int s = ptot;
    const int lane = t & 63;
#pragma unroll
    for (int o = 1; o < 64; o <<= 1) {
        int x = __shfl_up(s, o);
        if (lane >= o) s += x;
    }
    if (t == 63) w0tot = s;
    __syncthreads();
    if (t >= 64 && t < BUCK_SZ) s += w0tot;
    if (t < BUCK_SZ) {
        int ex = s - ptot;
        cur4[0][t] = ex;
        cur4[1][t] = ex + c0;
        cur4[2][t] = ex + c0 + c1;
        cur4[3][t] = ex + c0 + c1 + c2;
        int node = nbase + t;
        if (node < N_NODES) {
            rowbeg[node] = bb + ex;
            deg[node] = tot;
            dinv[node] = rsqrtf((float)(tot + 1));
        }
        for (int i = tot; i < ptot; ++i) csr_src[bb + ex + i] = DUMMY;
    }
    __syncthreads();
#pragma unroll
    for (int k = 0; k < SORT_SLOTS; ++k) {
        if (ed[k] != 0xFFFFFFFFu) {
            int dl = (ed[k] >> 17) & (BUCK_SZ - 1);
            int pos = bb + atomicAdd(&cur4[w][dl], 1);
            csr_src[pos] = (int)(ed[k] & 0x1FFFF);
        }
    }
}

// ---------------------------------------------------------------------------
// 3. h0b = bf16((x @ W1) * dinv[row]); 32 rows/block, 4 outputs/thread
// ---------------------------------------------------------------------------
__global__ __launch_bounds__(256) void k_gemm1(const float* __restrict__ x,
                                               const float* __restrict__ W1,
                                               const float* __restrict__ dinv,
                                               uint16_t* __restrict__ h0b) {
    __shared__ __align__(16) float w1s[NFEAT * HIDDEN];
    __shared__ __align__(16) float xs[32 * NFEAT];
    const int tid = threadIdx.x;
    for (int i = tid; i < NFEAT * HIDDEN / 4; i += 256)
        ((fx4*)w1s)[i] = ((const fx4*)W1)[i];
    const int row0 = blockIdx.x * 32;
    const fx4* xb = (const fx4*)(x + (size_t)row0 * NFEAT);
    for (int i = tid; i < 800; i += 256)
        ((fx4*)xs)[i] = __builtin_nontemporal_load(&xb[i]);
    __syncthreads();
    const int c = tid & 31, r0 = tid >> 5;
    float a0 = 0.f, a1 = 0.f, a2 = 0.f, a3 = 0.f;
#pragma unroll 4
    for (int k = 0; k < NFEAT; ++k) {
        float wv = w1s[k * HIDDEN + c];
        a0 = fmaf(xs[(r0)      * NFEAT + k], wv, a0);
        a1 = fmaf(xs[(r0 + 8)  * NFEAT + k], wv, a1);
        a2 = fmaf(xs[(r0 + 16) * NFEAT + k], wv, a2);
        a3 = fmaf(xs[(r0 + 24) * NFEAT + k], wv, a3);
    }
    const int r = row0 + r0;
    h0b[(size_t)(r)      * HIDDEN + c] = f2bf(a0 * dinv[r]);
    h0b[(size_t)(r + 8)  * HIDDEN + c] = f2bf(a1 * dinv[r + 8]);
    h0b[(size_t)(r + 16) * HIDDEN + c] = f2bf(a2 * dinv[r + 16]);
    h0b[(size_t)(r + 24) * HIDDEN + c] = f2bf(a3 * dinv[r + 24]);
}

// ---------------------------------------------------------------------------
// 4. Layer 1: 8 lanes/node (uint2, cols 4l..4l+3), rows padded to x8 ->
//    branchless 8-edge batches, 8 gathers in flight, 8-deep index prefetch.
//    Grid = 3125 blocks (~12/CU demand) with guaranteed 8 blocks/CU.
// ---------------------------------------------------------------------------
__global__ __launch_bounds__(256, 8) void k_l1(const int* __restrict__ rowbeg,
                                               const int* __restrict__ deg,
                                               const int* __restrict__ csr_src,
                                               const float* __restrict__ dinv,
                                               const uint2* __restrict__ h0u,
                                               const float* __restrict__ b1,
                                               const float* __restrict__ W2,
                                               float* __restrict__ h2s) {
    const int t = blockIdx.x * 256 + threadIdx.x;
    const int n = t >> 3;        // 32 nodes per block (grid exact)
    const int l = t & 7;         // columns 4l..4l+3
    uint2 self = h0u[(size_t)n * 8 + l];
    float aL0 = bflo(self.x), aH0 = bfhi(self.x);
    float aL1 = bflo(self.y), aH1 = bfhi(self.y);
    const int beg = rowbeg[n];
    const int d = deg[n];
    const int end8 = beg + ((d + 7) & ~7);
    int j = beg;
    int s0, s1, s2, s3, s4, s5, s6, s7;
    if (j < end8) {
        s0 = csr_src[j];     s1 = csr_src[j + 1];
        s2 = csr_src[j + 2]; s3 = csr_src[j + 3];
        s4 = csr_src[j + 4]; s5 = csr_src[j + 5];
        s6 = csr_src[j + 6]; s7 = csr_src[j + 7];
    }
    for (; j < end8; j += 8) {
        uint2 u0 = h0u[(size_t)s0 * 8 + l];
        uint2 u1 = h0u[(size_t)s1 * 8 + l];
        uint2 u2 = h0u[(size_t)s2 * 8 + l];
        uint2 u3 = h0u[(size_t)s3 * 8 + l];
        uint2 u4 = h0u[(size_t)s4 * 8 + l];
        uint2 u5 = h0u[(size_t)s5 * 8 + l];
        uint2 u6 = h0u[(size_t)s6 * 8 + l];
        uint2 u7 = h0u[(size_t)s7 * 8 + l];
        int pj = (j + 16 <= end8) ? j + 8 : beg;
        s0 = csr_src[pj];     s1 = csr_src[pj + 1];
        s2 = csr_src[pj + 2]; s3 = csr_src[pj + 3];
        s4 = csr_src[pj + 4]; s5 = csr_src[pj + 5];
        s6 = csr_src[pj + 6]; s7 = csr_src[pj + 7];
        aL0 += bflo(u0.x); aH0 += bfhi(u0.x); aL1 += bflo(u0.y); aH1 += bfhi(u0.y);
        aL0 += bflo(u1.x); aH0 += bfhi(u1.x); aL1 += bflo(u1.y); aH1 += bfhi(u1.y);
        aL0 += bflo(u2.x); aH0 += bfhi(u2.x); aL1 += bflo(u2.y); aH1 += bfhi(u2.y);
        aL0 += bflo(u3.x); aH0 += bfhi(u3.x); aL1 += bflo(u3.y); aH1 += bfhi(u3.y);
        aL0 += bflo(u4.x); aH0 += bfhi(u4.x); aL1 += bflo(u4.y); aH1 += bfhi(u4.y);
        aL0 += bflo(u5.x); aH0 += bfhi(u5.x); aL1 += bflo(u5.y); aH1 += bfhi(u5.y);
        aL0 += bflo(u6.x); aH0 += bfhi(u6.x); aL1 += bflo(u6.y); aH1 += bfhi(u6.y);
        aL0 += bflo(u7.x); aH0 += bfhi(u7.x); aL1 += bflo(u7.y); aH1 += bfhi(u7.y);
    }
    const int c0 = 4 * l;
    const float din = dinv[n];
    float v0 = fmaxf(fmaf(aL0, din, b1[c0 + 0]), 0.0f);
    float v1 = fmaxf(fmaf(aH0, din, b1[c0 + 1]), 0.0f);
    float v2 = fmaxf(fmaf(aL1, din, b1[c0 + 2]), 0.0f);
    float v3 = fmaxf(fmaf(aH1, din, b1[c0 + 3]), 0.0f);
    const uint32_t fb = (uint32_t)(n * HIDDEN + c0);
    v0 = dropout_keep(fb + 0) ? v0 * 1.25f : 0.0f;
    v1 = dropout_keep(fb + 1) ? v1 * 1.25f : 0.0f;
    v2 = dropout_keep(fb + 2) ? v2 * 1.25f : 0.0f;
    v3 = dropout_keep(fb + 3) ? v3 * 1.25f : 0.0f;
    float p0 = v0 * W2[(c0 + 0) * 2] + v1 * W2[(c0 + 1) * 2]
             + v2 * W2[(c0 + 2) * 2] + v3 * W2[(c0 + 3) * 2];
    float p1 = v0 * W2[(c0 + 0) * 2 + 1] + v1 * W2[(c0 + 1) * 2 + 1]
             + v2 * W2[(c0 + 2) * 2 + 1] + v3 * W2[(c0 + 3) * 2 + 1];
#pragma unroll
    for (int m = 4; m >= 1; m >>= 1) {
        p0 += __shfl_xor(p0, m);
        p1 += __shfl_xor(p1, m);
    }
    if (l == 0) {
        float2* o = (float2*)(h2s + (size_t)n * 2);
        *o = make_float2(p0 * din, p1 * din);
    }
}

// ---------------------------------------------------------------------------
// 5. Layer 2: 8 lanes/node over padded rows, 2x unrolled float2 gathers,
//    + b2 + log_softmax.
// ---------------------------------------------------------------------------
__global__ __launch_bounds__(256, 8) void k_l2(const int* __restrict__ rowbeg,
                                               const int* __restrict__ deg,
                                               const int* __restrict__ csr_src,
                                               const float* __restrict__ dinv,
                                               const float* __restrict__ h2s,
                                               const float* __restrict__ b2,
                                               float* __restrict__ out) {
    int t = blockIdx.x * 256 + threadIdx.x;
    int n = t >> 3;
    int l = t & 7;
    if (n >= N_NODES) return;
    float acc0 = 0.0f, acc1 = 0.0f;
    float bcc0 = 0.0f, bcc1 = 0.0f;
    if (l == 0) {
        float2 hn = ((const float2*)h2s)[n];
        acc0 = hn.x; acc1 = hn.y;
    }
    const int beg = rowbeg[n];
    const int end8 = beg + ((deg[n] + 7) & ~7);
    int j = beg + l;
    for (; j + 8 < end8; j += 16) {
        int s0 = __builtin_nontemporal_load(&csr_src[j]);
        int s1 = __builtin_nontemporal_load(&csr_src[j + 8]);
        float2 h0v = ((const float2*)h2s)[s0];
        float2 h1v = ((const float2*)h2s)[s1];
        acc0 += h0v.x; acc1 += h0v.y;
        bcc0 += h1v.x; bcc1 += h1v.y;
    }
    if (j < end8) {
        float2 hv = ((const float2*)h2s)[__builtin_nontemporal_load(&csr_src[j])];
        acc0 += hv.x; acc1 += hv.y;
    }
    acc0 += bcc0; acc1 += bcc1;
#pragma unroll
    for (int m = 4; m >= 1; m >>= 1) {
        acc0 += __shfl_xor(acc0, m);
        acc1 += __shfl_xor(acc1, m);
    }
    if (l == 0) {
        float din = dinv[n];
        float l0 = fmaf(acc0, din, b2[0]);
        float l1 = fmaf(acc1, din, b2[1]);
        float m = fmaxf(l0, l1);
        float lse = m + logf(expf(l0 - m) + expf(l1 - m));
        float2* o = (float2*)(out + (size_t)n * 2);
        *o = make_float2(l0 - lse, l1 - lse);
    }
}

// ---------------------------------------------------------------------------
// Launch
// ---------------------------------------------------------------------------
static inline size_t align_up(size_t x) { return (x + 255) & ~(size_t)255; }

extern "C" void kernel_launch(void* const* d_in, const int* in_sizes, int n_in,
                              void* d_out, int out_size, void* d_ws, size_t ws_size,
                              hipStream_t stream) {
    (void)n_in; (void)in_sizes; (void)out_size; (void)ws_size;

    const float* x  = (const float*)d_in[0];
    const int*   ei = (const int*)d_in[1];
    const float* W1 = (const float*)d_in[2];
    const float* b1 = (const float*)d_in[3];
    const float* W2 = (const float*)d_in[4];
    const float* b2 = (const float*)d_in[5];
    float* out = (float*)d_out;

    const int* src = ei;
    const int* dst = ei + N_EDGES;

    char* w = (char*)d_ws;
    size_t off = 0;
    int*      bcur   = (int*)(w + off);      off += align_up((size_t)NBUCK * 4);
    int*      rowbeg = (int*)(w + off);      off += align_up((size_t)N_NODES * 4);
    int*      deg    = (int*)(w + off);      off += align_up((size_t)N_NODES * 4);
    float*    dinv   = (float*)(w + off);    off += align_up((size_t)N_NODES * 4);
    uint32_t* part   = (uint32_t*)(w + off); off += align_up((size_t)NBUCK * PADB * 4);
    int*      csr    = (int*)(w + off);      off += align_up((size_t)NBUCK * PADB * 4);
    uint16_t* h0b    = (uint16_t*)(w + off); off += align_up((size_t)(N_NODES + 1) * HIDDEN * 2);
    float*    h2s    = (float*)(w + off);    off += align_up((size_t)(N_NODES + 1) * OUTC * 4);

    const int B = 256;
    k_init <<<(NBUCK + B - 1) / B, B, 0, stream>>>(bcur, (uint32_t*)h0b, h2s);
    k_part <<<PART_NB, 1024, 0, stream>>>(src, dst, bcur, part);
    k_sort <<<NBUCK, B, 0, stream>>>(part, bcur, csr, rowbeg, deg, dinv);
    k_gemm1<<<N_NODES / 32, B, 0, stream>>>(x, W1, dinv, h0b);
    k_l1   <<<(N_NODES * 8 + B - 1) / B, B, 0, stream>>>(rowbeg, deg, csr, dinv, (const uint2*)h0b, b1, W2, h2s);
    k_l2   <<<(N_NODES * 8 + B - 1) / B, B, 0, stream>>>(rowbeg, deg, csr, dinv, h2s, b2, out);
}

// Round 15
// 179.781 us; speedup vs baseline: 1.0156x; 1.0156x over previous
//
#include <hip/hip_runtime.h>
#include <stdint.h>
#include <math.h>

#define N_NODES   100000
#define N_EDGES   1600000
#define NFEAT     100
#define HIDDEN    32
#define OUTC      2

#define BUCK_BITS 7
#define BUCK_SZ   128
#define NBUCK     782                       // ceil(100000/128)
#define PADB      4096                      // padded window per bucket

#define PART_NB   256
#define PART_CHUNK ((N_EDGES + PART_NB - 1) / PART_NB)   // 6250

typedef float fx4 __attribute__((ext_vector_type(4)));

// ---------------------------------------------------------------------------
// JAX threefry2x32, key=(0,42), partitionable: bits(f) = o0^o1
// ---------------------------------------------------------------------------
__device__ __forceinline__ uint32_t rotl32(uint32_t x, int r) {
    return (x << r) | (x >> (32 - r));
}

__device__ __forceinline__ uint32_t threefry_bits(uint32_t f) {
    const uint32_t ks0 = 0u;
    const uint32_t ks1 = 42u;
    const uint32_t ks2 = 0x1BD11BDAu ^ 0u ^ 42u;
    uint32_t x0 = 0u + ks0;
    uint32_t x1 = f  + ks1;
#define TF_ROUND(r) { x0 += x1; x1 = rotl32(x1, (r)); x1 ^= x0; }
    TF_ROUND(13) TF_ROUND(15) TF_ROUND(26) TF_ROUND(6)
    x0 += ks1; x1 += ks2 + 1u;
    TF_ROUND(17) TF_ROUND(29) TF_ROUND(16) TF_ROUND(24)
    x0 += ks2; x1 += ks0 + 2u;
    TF_ROUND(13) TF_ROUND(15) TF_ROUND(26) TF_ROUND(6)
    x0 += ks0; x1 += ks1 + 3u;
    TF_ROUND(17) TF_ROUND(29) TF_ROUND(16) TF_ROUND(24)
    x0 += ks1; x1 += ks2 + 4u;
    TF_ROUND(13) TF_ROUND(15) TF_ROUND(26) TF_ROUND(6)
    x0 += ks2; x1 += ks0 + 5u;
#undef TF_ROUND
    return x0 ^ x1;
}

__device__ __forceinline__ bool dropout_keep(uint32_t f) {
    uint32_t bits = threefry_bits(f);
    float u = __uint_as_float((bits >> 9) | 0x3f800000u) - 1.0f;
    return u < 0.8f;
}

// float -> bf16 (RNE); packed bf16 pair unpack
__device__ __forceinline__ uint16_t f2bf(float f) {
    uint32_t b = __float_as_uint(f);
    uint32_t lsb = (b >> 16) & 1u;
    b += 0x7fffu + lsb;
    return (uint16_t)(b >> 16);
}
__device__ __forceinline__ float bflo(uint32_t u) {   // low ushort = even col
    return __uint_as_float(u << 16);
}
__device__ __forceinline__ float bfhi(uint32_t u) {   // high ushort = odd col
    return __uint_as_float(u & 0xffff0000u);
}

// ---------------------------------------------------------------------------
// 0. Seed bucket cursors to fixed padded bases
// ---------------------------------------------------------------------------
__global__ __launch_bounds__(256) void k_init(int* __restrict__ bcur) {
    int i = blockIdx.x * 256 + threadIdx.x;
    if (i < NBUCK) bcur[i] = i * PADB;
}

// ---------------------------------------------------------------------------
// 1. Partition into padded bucket windows; block-aggregated reservation +
//    4-way wave-split LDS cursors.
// ---------------------------------------------------------------------------
__global__ __launch_bounds__(1024) void k_part(const int* __restrict__ src,
                                               const int* __restrict__ dst,
                                               int* __restrict__ bcur,
                                               uint32_t* __restrict__ part) {
    __shared__ int h4[4][NBUCK];
    __shared__ int c4[4][NBUCK];
    const int t = threadIdx.x;
    const int w = (t >> 6) & 3;
    const int base = blockIdx.x * PART_CHUNK;
    const int lim = min(base + PART_CHUNK, N_EDGES);
    for (int i = t; i < 4 * NBUCK; i += 1024) ((int*)h4)[i] = 0;
    __syncthreads();
    for (int e = base + t; e < lim; e += 1024)
        atomicAdd(&h4[w][dst[e] >> BUCK_BITS], 1);
    __syncthreads();
    if (t < NBUCK) {
        int c0 = h4[0][t], c1 = h4[1][t], c2 = h4[2][t], c3 = h4[3][t];
        int tot = c0 + c1 + c2 + c3;
        int g = tot ? atomicAdd(&bcur[t], tot) : 0;
        c4[0][t] = g;
        c4[1][t] = g + c0;
        c4[2][t] = g + c0 + c1;
        c4[3][t] = g + c0 + c1 + c2;
    }
    __syncthreads();
    for (int e = base + t; e < lim; e += 1024) {
        int d = dst[e];
        int b = d >> BUCK_BITS;
        int pos = atomicAdd(&c4[w][b], 1);
        part[pos] = ((uint32_t)(d & (BUCK_SZ - 1)) << 17) | (uint32_t)src[e];
    }
}

// ---------------------------------------------------------------------------
// 2. Per-bucket counting sort -> csr (bucket-contiguous), rowbeg, deg, dinv
// ---------------------------------------------------------------------------
__global__ __launch_bounds__(256) void k_sort(const uint32_t* __restrict__ part,
                                              const int* __restrict__ bcur,
                                              int* __restrict__ csr_src,
                                              int* __restrict__ rowbeg,
                                              int* __restrict__ deg,
                                              float* __restrict__ dinv) {
    __shared__ int cnt4[4][BUCK_SZ];
    __shared__ int pref[BUCK_SZ];
    __shared__ int cur4[4][BUCK_SZ];
    const int b = blockIdx.x;
    const int t = threadIdx.x;
    const int w = t >> 6;
    const int nbase = b * BUCK_SZ;
    const int bb = b * PADB;
    const int be = bcur[b];            // final fill level
    for (int i = t; i < 4 * BUCK_SZ; i += 256) ((int*)cnt4)[i] = 0;
    __syncthreads();
    for (int j = bb + t; j < be; j += 256)
        atomicAdd(&cnt4[w][(part[j] >> 17) & (BUCK_SZ - 1)], 1);
    __syncthreads();
    int c0 = 0, c1 = 0, c2 = 0, tot = 0;
    if (t < BUCK_SZ) {
        c0 = cnt4[0][t]; c1 = cnt4[1][t]; c2 = cnt4[2][t];
        tot = c0 + c1 + c2 + cnt4[3][t];
        pref[t] = tot;
    }
    __syncthreads();
#pragma unroll
    for (int off = 1; off < BUCK_SZ; off <<= 1) {
        int v = (t >= off && t < BUCK_SZ) ? pref[t - off] : 0;
        __syncthreads();
        if (t < BUCK_SZ) pref[t] += v;
        __syncthreads();
    }
    if (t < BUCK_SZ) {
        int ex = pref[t] - tot;
        cur4[0][t] = ex;
        cur4[1][t] = ex + c0;
        cur4[2][t] = ex + c0 + c1;
        cur4[3][t] = ex + c0 + c1 + c2;
        int node = nbase + t;
        if (node < N_NODES) {
            rowbeg[node] = bb + ex;
            deg[node] = tot;
            dinv[node] = rsqrtf((float)(tot + 1));
        }
    }
    __syncthreads();
    for (int j = bb + t; j < be; j += 256) {
        uint32_t v = part[j];
        int dl = (v >> 17) & (BUCK_SZ - 1);
        int pos = bb + atomicAdd(&cur4[w][dl], 1);
        csr_src[pos] = (int)(v & 0x1FFFF);
    }
}

// ---------------------------------------------------------------------------
// 3. h0b = bf16((x @ W1) * dinv[row]); 32 rows/block, 4 outputs/thread
// ---------------------------------------------------------------------------
__global__ __launch_bounds__(256) void k_gemm1(const float* __restrict__ x,
                                               const float* __restrict__ W1,
                                               const float* __restrict__ dinv,
                                               uint16_t* __restrict__ h0b) {
    __shared__ __align__(16) float w1s[NFEAT * HIDDEN];
    __shared__ __align__(16) float xs[32 * NFEAT];
    const int tid = threadIdx.x;
    for (int i = tid; i < NFEAT * HIDDEN / 4; i += 256)
        ((fx4*)w1s)[i] = ((const fx4*)W1)[i];
    const int row0 = blockIdx.x * 32;
    const fx4* xb = (const fx4*)(x + (size_t)row0 * NFEAT);
    for (int i = tid; i < 800; i += 256)
        ((fx4*)xs)[i] = __builtin_nontemporal_load(&xb[i]);
    __syncthreads();
    const int c = tid & 31, r0 = tid >> 5;
    float a0 = 0.f, a1 = 0.f, a2 = 0.f, a3 = 0.f;
#pragma unroll 4
    for (int k = 0; k < NFEAT; ++k) {
        float wv = w1s[k * HIDDEN + c];
        a0 = fmaf(xs[(r0)      * NFEAT + k], wv, a0);
        a1 = fmaf(xs[(r0 + 8)  * NFEAT + k], wv, a1);
        a2 = fmaf(xs[(r0 + 16) * NFEAT + k], wv, a2);
        a3 = fmaf(xs[(r0 + 24) * NFEAT + k], wv, a3);
    }
    const int r = row0 + r0;
    h0b[(size_t)(r)      * HIDDEN + c] = f2bf(a0 * dinv[r]);
    h0b[(size_t)(r + 8)  * HIDDEN + c] = f2bf(a1 * dinv[r + 8]);
    h0b[(size_t)(r + 16) * HIDDEN + c] = f2bf(a2 * dinv[r + 16]);
    h0b[(size_t)(r + 24) * HIDDEN + c] = f2bf(a3 * dinv[r + 24]);
}

// ---------------------------------------------------------------------------
// 4. Layer 1: 8 lanes/node, uint2 (4xbf16) gathers => 8 edges per wave
//    instruction; software-pipelined index prefetch.
// ---------------------------------------------------------------------------
__global__ __launch_bounds__(256) void k_l1(const int* __restrict__ rowbeg,
                                            const int* __restrict__ deg,
                                            const int* __restrict__ csr_src,
                                            const float* __restrict__ dinv,
                                            const uint2* __restrict__ h0u,
                                            const float* __restrict__ b1,
                                            const float* __restrict__ W2,
                                            float* __restrict__ h2s) {
    const int t = blockIdx.x * 256 + threadIdx.x;
    const int n = t >> 3;        // 32 nodes per block (grid exact)
    const int l = t & 7;         // lane in 8-group; columns 4l..4l+3
    uint2 self = h0u[(size_t)n * 8 + l];
    float aL0 = bflo(self.x), aH0 = bfhi(self.x);
    float aL1 = bflo(self.y), aH1 = bfhi(self.y);
    const int beg = rowbeg[n];
    const int d = deg[n];
    const int end = beg + d;
    const int mainEnd = beg + (d & ~3);
    int j = beg;
    int s0, s1, s2, s3;
    if (j < mainEnd) {
        s0 = csr_src[j]; s1 = csr_src[j + 1];
        s2 = csr_src[j + 2]; s3 = csr_src[j + 3];
    }
    for (; j < mainEnd; j += 4) {
        uint2 u0 = h0u[(size_t)s0 * 8 + l];
        uint2 u1 = h0u[(size_t)s1 * 8 + l];
        uint2 u2 = h0u[(size_t)s2 * 8 + l];
        uint2 u3 = h0u[(size_t)s3 * 8 + l];
        int pj = (j + 8 <= mainEnd) ? j + 4 : beg;
        s0 = csr_src[pj];     s1 = csr_src[pj + 1];
        s2 = csr_src[pj + 2]; s3 = csr_src[pj + 3];
        aL0 += bflo(u0.x); aH0 += bfhi(u0.x); aL1 += bflo(u0.y); aH1 += bfhi(u0.y);
        aL0 += bflo(u1.x); aH0 += bfhi(u1.x); aL1 += bflo(u1.y); aH1 += bfhi(u1.y);
        aL0 += bflo(u2.x); aH0 += bfhi(u2.x); aL1 += bflo(u2.y); aH1 += bfhi(u2.y);
        aL0 += bflo(u3.x); aH0 += bfhi(u3.x); aL1 += bflo(u3.y); aH1 += bfhi(u3.y);
    }
    for (; j < end; ++j) {
        uint2 u = h0u[(size_t)csr_src[j] * 8 + l];
        aL0 += bflo(u.x); aH0 += bfhi(u.x); aL1 += bflo(u.y); aH1 += bfhi(u.y);
    }
    const int c0 = 4 * l, c1 = c0 + 1, c2 = c0 + 2, c3 = c0 + 3;
    const float din = dinv[n];
    float v0 = fmaxf(fmaf(aL0, din, b1[c0]), 0.0f);
    float v1 = fmaxf(fmaf(aH0, din, b1[c1]), 0.0f);
    float v2 = fmaxf(fmaf(aL1, din, b1[c2]), 0.0f);
    float v3 = fmaxf(fmaf(aH1, din, b1[c3]), 0.0f);
    const uint32_t fb = (uint32_t)(n * HIDDEN);
    v0 = dropout_keep(fb + c0) ? v0 * 1.25f : 0.0f;
    v1 = dropout_keep(fb + c1) ? v1 * 1.25f : 0.0f;
    v2 = dropout_keep(fb + c2) ? v2 * 1.25f : 0.0f;
    v3 = dropout_keep(fb + c3) ? v3 * 1.25f : 0.0f;
    float p0 = v0 * W2[c0 * 2] + v1 * W2[c1 * 2] + v2 * W2[c2 * 2] + v3 * W2[c3 * 2];
    float p1 = v0 * W2[c0 * 2 + 1] + v1 * W2[c1 * 2 + 1] + v2 * W2[c2 * 2 + 1] + v3 * W2[c3 * 2 + 1];
#pragma unroll
    for (int m = 4; m >= 1; m >>= 1) {
        p0 += __shfl_xor(p0, m);
        p1 += __shfl_xor(p1, m);
    }
    if (l == 0) {
        float2* o = (float2*)(h2s + (size_t)n * 2);
        *o = make_float2(p0 * din, p1 * din);
    }
}

// ---------------------------------------------------------------------------
// 5. Layer 2: register-pull, 8 lanes/node, 2x unrolled float2 gathers,
//    + b2 + log_softmax.
// ---------------------------------------------------------------------------
__global__ __launch_bounds__(256) void k_l2(const int* __restrict__ rowbeg,
                                            const int* __restrict__ deg,
                                            const int* __restrict__ csr_src,
                                            const float* __restrict__ dinv,
                                            const float* __restrict__ h2s,
                                            const float* __restrict__ b2,
                                            float* __restrict__ out) {
    int t = blockIdx.x * 256 + threadIdx.x;
    int n = t >> 3;
    int l = t & 7;
    if (n >= N_NODES) return;
    float acc0 = 0.0f, acc1 = 0.0f;
    float bcc0 = 0.0f, bcc1 = 0.0f;
    if (l == 0) {
        float2 hn = ((const float2*)h2s)[n];
        acc0 = hn.x; acc1 = hn.y;
    }
    const int beg = rowbeg[n];
    const int end = beg + deg[n];
    int j = beg + l;
    for (; j + 8 < end; j += 16) {
        int s0 = __builtin_nontemporal_load(&csr_src[j]);
        int s1 = __builtin_nontemporal_load(&csr_src[j + 8]);
        float2 h0v = ((const float2*)h2s)[s0];
        float2 h1v = ((const float2*)h2s)[s1];
        acc0 += h0v.x; acc1 += h0v.y;
        bcc0 += h1v.x; bcc1 += h1v.y;
    }
    if (j < end) {
        float2 hv = ((const float2*)h2s)[__builtin_nontemporal_load(&csr_src[j])];
        acc0 += hv.x; acc1 += hv.y;
    }
    acc0 += bcc0; acc1 += bcc1;
#pragma unroll
    for (int m = 4; m >= 1; m >>= 1) {
        acc0 += __shfl_xor(acc0, m);
        acc1 += __shfl_xor(acc1, m);
    }
    if (l == 0) {
        float din = dinv[n];
        float l0 = fmaf(acc0, din, b2[0]);
        float l1 = fmaf(acc1, din, b2[1]);
        float m = fmaxf(l0, l1);
        float lse = m + logf(expf(l0 - m) + expf(l1 - m));
        float2* o = (float2*)(out + (size_t)n * 2);
        *o = make_float2(l0 - lse, l1 - lse);
    }
}

// ---------------------------------------------------------------------------
// Launch
// ---------------------------------------------------------------------------
static inline size_t align_up(size_t x) { return (x + 255) & ~(size_t)255; }

extern "C" void kernel_launch(void* const* d_in, const int* in_sizes, int n_in,
                              void* d_out, int out_size, void* d_ws, size_t ws_size,
                              hipStream_t stream) {
    (void)n_in; (void)in_sizes; (void)out_size; (void)ws_size;

    const float* x  = (const float*)d_in[0];
    const int*   ei = (const int*)d_in[1];
    const float* W1 = (const float*)d_in[2];
    const float* b1 = (const float*)d_in[3];
    const float* W2 = (const float*)d_in[4];
    const float* b2 = (const float*)d_in[5];
    float* out = (float*)d_out;

    const int* src = ei;
    const int* dst = ei + N_EDGES;

    char* w = (char*)d_ws;
    size_t off = 0;
    int*      bcur   = (int*)(w + off);      off += align_up((size_t)NBUCK * 4);
    int*      rowbeg = (int*)(w + off);      off += align_up((size_t)N_NODES * 4);
    int*      deg    = (int*)(w + off);      off += align_up((size_t)N_NODES * 4);
    float*    dinv   = (float*)(w + off);    off += align_up((size_t)N_NODES * 4);
    uint32_t* part   = (uint32_t*)(w + off); off += align_up((size_t)NBUCK * PADB * 4);
    int*      csr    = (int*)(w + off);      off += align_up((size_t)NBUCK * PADB * 4);
    uint16_t* h0b    = (uint16_t*)(w + off); off += align_up((size_t)N_NODES * HIDDEN * 2);
    float*    h2s    = (float*)(w + off);    off += align_up((size_t)N_NODES * OUTC * 4);

    const int B = 256;
    k_init <<<(NBUCK + B - 1) / B, B, 0, stream>>>(bcur);
    k_part <<<PART_NB, 1024, 0, stream>>>(src, dst, bcur, part);
    k_sort <<<NBUCK, B, 0, stream>>>(part, bcur, csr, rowbeg, deg, dinv);
    k_gemm1<<<N_NODES / 32, B, 0, stream>>>(x, W1, dinv, h0b);
    k_l1   <<<(N_NODES * 8 + B - 1) / B, B, 0, stream>>>(rowbeg, deg, csr, dinv, (const uint2*)h0b, b1, W2, h2s);
    k_l2   <<<(N_NODES * 8 + B - 1) / B, B, 0, stream>>>(rowbeg, deg, csr, dinv, h2s, b2, out);
}